// Round 7
// baseline (932.773 us; speedup 1.0000x reference)
//
#include <hip/hip_runtime.h>

// ArcMarginProduct: out[b,c] = S * (c==label[b] ? phi : cos)
//   cos = <input_b/||input_b||, weight_c/||weight_c||>
//   phi = cos*cos(m) - sine*sin(m), fallback cos - S*sin(m)*m if cos <= cos(pi-m)
// B=1024, D=512, C=100000. fp32 in/out; bf16 MFMA inside.
//
// R1/R2: prenorm W to bf16 (FETCH 804->55 MB), XCD swizzle, 286 us gemm.
// R3/R5/R6: gl16 staging, counted-vmcnt pipelines, occupancy push: 257-315 us.
//     All barrier-synced 128^2 variants stuck with every pipe <20% busy,
//     ~6000 cyc per 300-cyc K-iter => barrier convoy dominates.
// R7: ZERO-SYNC experiment — no LDS, no barriers. Each wave owns a private
//     64x64 sub-tile; A and W fragments loaded global->VGPR directly in MFMA
//     fragment layout (same 16-row x 64 B segment pattern as the old gl16s;
//     A is L1/L2-resident, 2x re-read amplification absorbed at <20% L2 use).
//     Compiler free-pipelines a pure dependence graph; waves fully independent.

#define MDIM 1024
#define KDIM 512
#define NCLS 100000

#define BM 128
#define BN 128
#define BK 32
#define LDST 40   // fallback kernel only: padded row stride

#define NTILES ((NCLS + BN - 1) / BN)   // 782
#define NWG (8 * NTILES)                // 6256, divisible by 8

typedef unsigned short u16;
typedef unsigned int u32;
typedef short s16x8 __attribute__((ext_vector_type(8)));
typedef float f32x4 __attribute__((ext_vector_type(4)));

// round-to-nearest-even fp32 -> bf16, two values packed into a u32
__device__ __forceinline__ u32 pk2(float a, float b) {
  u32 ua = __builtin_bit_cast(u32, a);
  u32 ub = __builtin_bit_cast(u32, b);
  ua += 0x7FFFu + ((ua >> 16) & 1u);
  ub += 0x7FFFu + ((ub >> 16) & 1u);
  return (ua >> 16) | (ub & 0xFFFF0000u);
}

// ---- Kernel 1: L2-normalize input rows, store bf16 row-major [1024][512] ----
__global__ __launch_bounds__(256) void norm_input_kernel(const float* __restrict__ in,
                                                         u16* __restrict__ abf) {
  const int row = blockIdx.x;
  const int tid = threadIdx.x;
  const float2 v = *reinterpret_cast<const float2*>(in + (size_t)row * KDIM + 2 * tid);
  float ss = v.x * v.x + v.y * v.y;
#pragma unroll
  for (int off = 32; off > 0; off >>= 1) ss += __shfl_down(ss, off);
  __shared__ float part[4];
  if ((tid & 63) == 0) part[tid >> 6] = ss;
  __syncthreads();
  const float tot = part[0] + part[1] + part[2] + part[3];
  const float rn = 1.0f / fmaxf(sqrtf(tot), 1e-12f);  // F.normalize: x / max(||x||, eps)
  reinterpret_cast<u32*>(abf)[row * (KDIM / 2) + tid] = pk2(v.x * rn, v.y * rn);
}

// ---- Kernel 1b: L2-normalize weight rows, store bf16 row-major [100000][512] ----
__global__ __launch_bounds__(256) void norm_weight_kernel(const float* __restrict__ W,
                                                          u16* __restrict__ wbf) {
  const int row = blockIdx.x * 4 + (threadIdx.x >> 6);
  const int lane = threadIdx.x & 63;
  const float* p = W + (size_t)row * KDIM + lane * 8;
  const float4 v0 = *reinterpret_cast<const float4*>(p);
  const float4 v1 = *reinterpret_cast<const float4*>(p + 4);
  float ss = v0.x * v0.x + v0.y * v0.y + v0.z * v0.z + v0.w * v0.w
           + v1.x * v1.x + v1.y * v1.y + v1.z * v1.z + v1.w * v1.w;
#pragma unroll
  for (int off = 32; off > 0; off >>= 1) ss += __shfl_xor(ss, off);
  const float rn = 1.0f / fmaxf(sqrtf(ss), 1e-12f);
  uint4 o;
  o.x = pk2(v0.x * rn, v0.y * rn);
  o.y = pk2(v0.z * rn, v0.w * rn);
  o.z = pk2(v1.x * rn, v1.y * rn);
  o.w = pk2(v1.z * rn, v1.w * rn);
  *reinterpret_cast<uint4*>(wbf + (size_t)row * KDIM + lane * 8) = o;
}

// ---- Kernel 2 (main): C = Anorm * Wnorm^T, both bf16, fused ArcFace epilogue ----
// 128x128 per block, 4 waves 2x2, each wave an INDEPENDENT 64x64 via 4x4 of
// 16x16x32 MFMA. No LDS, no barriers: fragments loaded straight from global.
//   A frag (i): lane(ln,kq) reads 16B at A[(m0+wm+16i+ln)*512 + kt*32 + kq*8]
//   W frag (j): lane(ln,kq) reads 16B at W[(n0+wn+16j+ln)*512 + kt*32 + kq*8]
// Per load instr: 16 rows x 64 B segments — identical pattern to R6's gl16.
// Grid: 1D, bijective XCD swizzle, M fastest within an XCD (W L2-resident).
__global__ __launch_bounds__(256, 3) void arcface_gemm_bf16(const u16* __restrict__ Abf,
                                                            const u16* __restrict__ Wbf,
                                                            const int* __restrict__ label,
                                                            float* __restrict__ out) {
  const int tid = threadIdx.x;
  const int orig = blockIdx.x;
  const int wg = (orig & 7) * NTILES + (orig >> 3);
  const int m0 = (wg & 7) * BM;
  const int n0 = (wg >> 3) * BN;

  const int lane = tid & 63;
  const int wv = tid >> 6;
  const int wm = (wv & 1) * 64;
  const int wn = (wv >> 1) * 64;
  const int ln = lane & 15;   // MFMA frag: row (A) / col-row (B); C/D col
  const int kq = lane >> 4;   // k-slice quad; C/D row-group

  // per-lane fragment base pointers (compile-time-indexed arrays, unrolled)
  const u16* ap[4];
  const u16* wp[4];
#pragma unroll
  for (int i = 0; i < 4; ++i)
    ap[i] = Abf + (size_t)(m0 + wm + 16 * i + ln) * KDIM + kq * 8;
#pragma unroll
  for (int j = 0; j < 4; ++j) {
    int wrow = n0 + wn + 16 * j + ln;
    if (wrow >= NCLS) wrow = NCLS - 1;  // clamp loads; stores guarded
    wp[j] = Wbf + (size_t)wrow * KDIM + kq * 8;
  }

  f32x4 acc[4][4] = {};

#pragma unroll
  for (int kt = 0; kt < KDIM / BK; ++kt) {
    s16x8 af[4], wf[4];
#pragma unroll
    for (int i = 0; i < 4; ++i)
      af[i] = *(const s16x8*)(ap[i] + kt * BK);
#pragma unroll
    for (int j = 0; j < 4; ++j)
      wf[j] = *(const s16x8*)(wp[j] + kt * BK);
#pragma unroll
    for (int i = 0; i < 4; ++i)
#pragma unroll
      for (int j = 0; j < 4; ++j)
        acc[i][j] = __builtin_amdgcn_mfma_f32_16x16x32_bf16(af[i], wf[j], acc[i][j], 0, 0, 0);
  }

  // epilogue: C/D layout col = lane&15, row = (lane>>4)*4 + reg  [verified m89/m91]
  // row-major store order: per (i,rg) the 4 j-stores hit one 256B row segment.
  constexpr float S_ = 30.0f;
  constexpr float COS_M = 0.87758256189037276f;
  constexpr float SIN_M = 0.47942553860420301f;
  constexpr float TH_ = -0.87758256189037276f;       // cos(pi - 0.5)
  constexpr float FALLB = 30.0f * 0.47942553860420301f * 0.5f;  // S*sin(m)*m

#pragma unroll
  for (int i = 0; i < 4; ++i) {
#pragma unroll
    for (int rg = 0; rg < 4; ++rg) {
      const int lrow = wm + 16 * i + 4 * kq + rg;
      const int row_lbl = label[m0 + lrow];   // L1-broadcast across the 16 ln lanes
      float* const orow = out + (size_t)(m0 + lrow) * NCLS;
#pragma unroll
      for (int j = 0; j < 4; ++j) {
        const int gcol = n0 + wn + 16 * j + ln;
        if (gcol < NCLS) {
          const float cosv = acc[i][j][rg];
          float o = S_ * cosv;
          if (gcol == row_lbl) {
            const float s2 = fmaxf(1.0f - cosv * cosv, 0.0f);
            const float sine = sqrtf(s2);
            float phi = cosv * COS_M - sine * SIN_M;
            phi = (cosv > TH_) ? phi : (cosv - FALLB);
            o = S_ * phi;
          }
          orow[gcol] = o;
        }
      }
    }
  }
}

// ---- Fallback kernel (ws too small for bf16 W): previous proven fused version ----
__global__ __launch_bounds__(256) void arcface_gemm(const u16* __restrict__ Abf,
                                                    const float* __restrict__ W,
                                                    const int* __restrict__ label,
                                                    float* __restrict__ out) {
  __shared__ u16 lA[BM * LDST];
  __shared__ u16 lW[BN * LDST];
  __shared__ float rnw[BN];
  __shared__ int lbl[BM];

  const int tid = threadIdx.x;
  const int m0 = blockIdx.x * BM;
  const int n0 = blockIdx.y * BN;

  if (tid < BM) lbl[tid] = label[m0 + tid];

  const int r = tid >> 1;
  const int half = tid & 1;
  int c = n0 + r;
  if (c >= NCLS) c = NCLS - 1;

  const u16* aptr = Abf + (size_t)(m0 + r) * KDIM + half * 16;
  const float* wptr = W + (size_t)c * KDIM + half * 16;

  uint4 a0 = *(const uint4*)(aptr);
  uint4 a1 = *(const uint4*)(aptr + 8);
  float4 w0 = *(const float4*)(wptr);
  float4 w1 = *(const float4*)(wptr + 4);
  float4 w2 = *(const float4*)(wptr + 8);
  float4 w3 = *(const float4*)(wptr + 12);

  f32x4 acc[4][4] = {};
  float ss = 0.0f;

  const int lane = tid & 63;
  const int wv = tid >> 6;
  const int wm = (wv & 1) * 64;
  const int wn = (wv >> 1) * 64;
  const int ln = lane & 15;
  const int kq = lane >> 4;

  const int aw = r * LDST + half * 16;

  for (int kt = 0; kt < KDIM / BK; ++kt) {
    __syncthreads();
    *(uint4*)&lA[aw] = a0;
    *(uint4*)&lA[aw + 8] = a1;
    ss += w0.x * w0.x + w0.y * w0.y + w0.z * w0.z + w0.w * w0.w;
    ss += w1.x * w1.x + w1.y * w1.y + w1.z * w1.z + w1.w * w1.w;
    ss += w2.x * w2.x + w2.y * w2.y + w2.z * w2.z + w2.w * w2.w;
    ss += w3.x * w3.x + w3.y * w3.y + w3.z * w3.z + w3.w * w3.w;
    uint4 p0, p1;
    p0.x = pk2(w0.x, w0.y); p0.y = pk2(w0.z, w0.w);
    p0.z = pk2(w1.x, w1.y); p0.w = pk2(w1.z, w1.w);
    p1.x = pk2(w2.x, w2.y); p1.y = pk2(w2.z, w2.w);
    p1.z = pk2(w3.x, w3.y); p1.w = pk2(w3.z, w3.w);
    *(uint4*)&lW[aw] = p0;
    *(uint4*)&lW[aw + 8] = p1;
    __syncthreads();

    if (kt < KDIM / BK - 1) {
      const u16* ap = aptr + (kt + 1) * BK;
      a0 = *(const uint4*)(ap);
      a1 = *(const uint4*)(ap + 8);
      const float* wp = wptr + (kt + 1) * BK;
      w0 = *(const float4*)(wp);
      w1 = *(const float4*)(wp + 4);
      w2 = *(const float4*)(wp + 8);
      w3 = *(const float4*)(wp + 12);
    }

    s16x8 af[4], wf[4];
#pragma unroll
    for (int i = 0; i < 4; ++i)
      af[i] = *(const s16x8*)&lA[(wm + 16 * i + ln) * LDST + kq * 8];
#pragma unroll
    for (int j = 0; j < 4; ++j)
      wf[j] = *(const s16x8*)&lW[(wn + 16 * j + ln) * LDST + kq * 8];
#pragma unroll
    for (int i = 0; i < 4; ++i)
#pragma unroll
      for (int j = 0; j < 4; ++j)
        acc[i][j] = __builtin_amdgcn_mfma_f32_16x16x32_bf16(af[i], wf[j], acc[i][j], 0, 0, 0);
  }

  const float sst = ss + __shfl_xor(ss, 1);
  if (half == 0) rnw[r] = 1.0f / fmaxf(sqrtf(sst), 1e-12f);
  __syncthreads();

  constexpr float S_ = 30.0f;
  constexpr float COS_M = 0.87758256189037276f;
  constexpr float SIN_M = 0.47942553860420301f;
  constexpr float TH_ = -0.87758256189037276f;
  constexpr float FALLB = 30.0f * 0.47942553860420301f * 0.5f;

#pragma unroll
  for (int i = 0; i < 4; ++i) {
    const int lrow_b = wm + 16 * i + 4 * kq;
#pragma unroll
    for (int j = 0; j < 4; ++j) {
      const int col = wn + 16 * j + ln;
      const int gcol = n0 + col;
      const float rw = rnw[col];
      if (gcol < NCLS) {
#pragma unroll
        for (int rg = 0; rg < 4; ++rg) {
          const int lrow = lrow_b + rg;
          const float cosv = acc[i][j][rg] * rw;
          float o = S_ * cosv;
          if (gcol == lbl[lrow]) {
            const float s2 = fmaxf(1.0f - cosv * cosv, 0.0f);
            const float sine = sqrtf(s2);
            float phi = cosv * COS_M - sine * SIN_M;
            phi = (cosv > TH_) ? phi : (cosv - FALLB);
            o = S_ * phi;
          }
          out[(size_t)(m0 + lrow) * NCLS + gcol] = o;
        }
      }
    }
  }
}

extern "C" void kernel_launch(void* const* d_in, const int* in_sizes, int n_in,
                              void* d_out, int out_size, void* d_ws, size_t ws_size,
                              hipStream_t stream) {
  const float* input = (const float*)d_in[0];
  const int* label = (const int*)d_in[1];
  const float* weight = (const float*)d_in[2];
  float* out = (float*)d_out;
  u16* abf = (u16*)d_ws;  // 1024*512 bf16 = 1 MB normalized input

  hipLaunchKernelGGL(norm_input_kernel, dim3(MDIM), dim3(256), 0, stream, input, abf);

  const size_t a_bytes = (size_t)MDIM * KDIM * sizeof(u16);
  const size_t w_bytes = (size_t)NCLS * KDIM * sizeof(u16);
  if (ws_size >= a_bytes + w_bytes) {
    u16* wbf = abf + (size_t)MDIM * KDIM;  // 100000*512 bf16 = 102.4 MB
    hipLaunchKernelGGL(norm_weight_kernel, dim3(NCLS / 4), dim3(256), 0, stream, weight, wbf);
    hipLaunchKernelGGL(arcface_gemm_bf16, dim3(NWG), dim3(256), 0, stream, abf, wbf, label, out);
  } else {
    dim3 grid(MDIM / BM, (NCLS + BN - 1) / BN);
    hipLaunchKernelGGL(arcface_gemm, grid, dim3(256), 0, stream, abf, weight, label, out);
  }
}

// Round 8
// 862.804 us; speedup vs baseline: 1.0811x; 1.0811x over previous
//
#include <hip/hip_runtime.h>

// ArcMarginProduct: out[b,c] = S * (c==label[b] ? phi : cos)
//   cos = <input_b/||input_b||, weight_c/||weight_c||>
//   phi = cos*cos(m) - sine*sin(m), fallback cos - S*sin(m)*m if cos <= cos(pi-m)
// B=1024, D=512, C=100000. fp32 in/out; bf16 MFMA inside.
//
// R1/R2: prenorm W to bf16 (FETCH 804->55 MB), XCD swizzle, 286 us gemm.
// R3/R5/R6: gl16 staging + counted-vmcnt pipelines: 257-315 us, all pipes <20%.
// R7: zero-sync direct fragment gathers: 466 us. KEY DATUM: divergent-load
//     count doubled vs R6 and time doubled. Bottleneck = TA/L1 cost of
//     16-line-divergent loads (the row-major fragment gather), not barriers.
// R8: PACKED OPERANDS. A and W stored as 1KB fragment tiles
//     [group16][kt][kq][ln][8e]; a fragment load = base + lane*16B = one
//     coalesced 1KB load (8 contiguous lines, the minimum). Gemm stays
//     zero-sync (no LDS/barriers); norm_weight becomes group-per-wave
//     two-pass with coalesced tile writes.

#define MDIM 1024
#define KDIM 512
#define NCLS 100000
#define NGRPW (NCLS / 16)   // 6250 W row-groups (exact)

#define BM 128
#define BN 128
#define BK 32
#define LDST 40   // fallback kernel only: padded row stride

#define NTILES ((NCLS + BN - 1) / BN)   // 782
#define NWG (8 * NTILES)                // 6256, divisible by 8

typedef unsigned short u16;
typedef unsigned int u32;
typedef short s16x8 __attribute__((ext_vector_type(8)));
typedef float f32x4 __attribute__((ext_vector_type(4)));

// round-to-nearest-even fp32 -> bf16, two values packed into a u32
__device__ __forceinline__ u32 pk2(float a, float b) {
  u32 ua = __builtin_bit_cast(u32, a);
  u32 ub = __builtin_bit_cast(u32, b);
  ua += 0x7FFFu + ((ua >> 16) & 1u);
  ub += 0x7FFFu + ((ub >> 16) & 1u);
  return (ua >> 16) | (ub & 0xFFFF0000u);
}

// ---- Kernel 1: L2-normalize input rows; write PACKED tiles + row-major copy ----
// Packed layout: tile t = (rowgroup g)*16 + kt is 1KB = 256 u32:
//   u32 idx = t*256 + kq*64 + (row&15)*4 + sub   (elems kt*32+kq*8+2*sub..+1)
// Thread tid holds elems 2tid..2tid+1 of its row: kt=tid>>4, kq=(tid>>2)&3, sub=tid&3.
__global__ __launch_bounds__(256) void norm_input_kernel(const float* __restrict__ in,
                                                         u32* __restrict__ apk,
                                                         u32* __restrict__ arm) {
  const int row = blockIdx.x;
  const int tid = threadIdx.x;
  const float2 v = *reinterpret_cast<const float2*>(in + (size_t)row * KDIM + 2 * tid);
  float ss = v.x * v.x + v.y * v.y;
#pragma unroll
  for (int off = 32; off > 0; off >>= 1) ss += __shfl_down(ss, off);
  __shared__ float part[4];
  if ((tid & 63) == 0) part[tid >> 6] = ss;
  __syncthreads();
  const float tot = part[0] + part[1] + part[2] + part[3];
  const float rn = 1.0f / fmaxf(sqrtf(tot), 1e-12f);  // F.normalize: x / max(||x||, eps)
  const u32 val = pk2(v.x * rn, v.y * rn);
  const int g = row >> 4, lnr = row & 15;
  const int kt = tid >> 4, kq = (tid >> 2) & 3, sub = tid & 3;
  apk[((g * 16 + kt) << 8) + (kq << 6) + (lnr << 2) + sub] = val;
  arm[row * (KDIM / 2) + tid] = val;  // row-major copy for the fallback kernel
}

// ---- Kernel 1b: L2-normalize W rows; write PACKED fragment tiles ----
// One wave per 16-row group G. Lane l=(kq*16+ln) owns row 16G+ln, k-slice kq.
// Pass 1: accumulate sum-of-squares (lane covers 1/4 of its row), reduce over
// the 4 kq-lanes sharing ln via shfl_xor(16),(32). Pass 2: re-read (L2-warm),
// scale, write tile (G,kt): 64 lanes x 16B = coalesced 1KB store.
__global__ __launch_bounds__(256) void norm_weight_kernel(const float* __restrict__ W,
                                                          u16* __restrict__ wpk) {
  const int G = blockIdx.x * 4 + (threadIdx.x >> 6);
  if (G >= NGRPW) return;   // no barriers below: divergent exit safe
  const int lane = threadIdx.x & 63;
  const int ln = lane & 15;
  const int kq = lane >> 4;
  const float* rp = W + (size_t)(16 * G + ln) * KDIM + kq * 8;
  float ss = 0.0f;
#pragma unroll
  for (int kt = 0; kt < 16; ++kt) {
    const float4 a = *reinterpret_cast<const float4*>(rp + kt * 32);
    const float4 b = *reinterpret_cast<const float4*>(rp + kt * 32 + 4);
    ss += a.x * a.x + a.y * a.y + a.z * a.z + a.w * a.w
        + b.x * b.x + b.y * b.y + b.z * b.z + b.w * b.w;
  }
  ss += __shfl_xor(ss, 16);
  ss += __shfl_xor(ss, 32);   // now = full-row sum for row 16G+ln
  const float rn = 1.0f / fmaxf(sqrtf(ss), 1e-12f);
#pragma unroll
  for (int kt = 0; kt < 16; ++kt) {
    const float4 a = *reinterpret_cast<const float4*>(rp + kt * 32);
    const float4 b = *reinterpret_cast<const float4*>(rp + kt * 32 + 4);
    uint4 o;
    o.x = pk2(a.x * rn, a.y * rn);
    o.y = pk2(a.z * rn, a.w * rn);
    o.z = pk2(b.x * rn, b.y * rn);
    o.w = pk2(b.z * rn, b.w * rn);
    *reinterpret_cast<uint4*>(wpk + (((size_t)G * 16 + kt) << 9) + lane * 8) = o;
  }
}

// ---- Kernel 2 (main): C = Apk * Wpk^T, both packed bf16, fused ArcFace epilogue ----
// 128x128 per block, 4 waves 2x2, each wave an independent 64x64 via 4x4 of
// 16x16x32 MFMA. No LDS, no barriers. Every fragment load is base + lane*16B
// over a 1KB packed tile: fully coalesced, 8 contiguous 128B lines.
// Grid: 1D, bijective XCD swizzle, M fastest within an XCD (W L2-resident).
__global__ __launch_bounds__(256, 3) void arcface_gemm_bf16(const u16* __restrict__ Apk,
                                                            const u16* __restrict__ Wpk,
                                                            const int* __restrict__ label,
                                                            float* __restrict__ out) {
  const int tid = threadIdx.x;
  const int orig = blockIdx.x;
  const int wg = (orig & 7) * NTILES + (orig >> 3);
  const int m0 = (wg & 7) * BM;
  const int n0 = (wg >> 3) * BN;

  const int lane = tid & 63;
  const int wv = tid >> 6;
  const int wm = (wv & 1) * 64;
  const int wn = (wv >> 1) * 64;
  const int ln = lane & 15;   // C/D col
  const int kq = lane >> 4;   // C/D row-group

  // fragment tile bases: tile index = group*16 + kt, tile = 512 u16 elems
  const u16* aT = Apk + ((size_t)((m0 + wm) >> 4) << 13) + lane * 8;
  const u16* wT[4];
#pragma unroll
  for (int j = 0; j < 4; ++j) {
    int gj = ((n0 + wn) >> 4) + j;
    if (gj > NGRPW - 1) gj = NGRPW - 1;   // clamp loads on last N-tile; stores guarded
    wT[j] = Wpk + ((size_t)gj << 13) + lane * 8;
  }

  f32x4 acc[4][4] = {};

#pragma unroll
  for (int kt = 0; kt < KDIM / BK; ++kt) {
    s16x8 af[4], wf[4];
#pragma unroll
    for (int i = 0; i < 4; ++i)
      af[i] = *(const s16x8*)(aT + ((i * 16 + kt) << 9));
#pragma unroll
    for (int j = 0; j < 4; ++j)
      wf[j] = *(const s16x8*)(wT[j] + (kt << 9));
#pragma unroll
    for (int i = 0; i < 4; ++i)
#pragma unroll
      for (int j = 0; j < 4; ++j)
        acc[i][j] = __builtin_amdgcn_mfma_f32_16x16x32_bf16(af[i], wf[j], acc[i][j], 0, 0, 0);
  }

  // epilogue: C/D layout col = lane&15, row = (lane>>4)*4 + reg  [verified m89/m91]
  constexpr float S_ = 30.0f;
  constexpr float COS_M = 0.87758256189037276f;
  constexpr float SIN_M = 0.47942553860420301f;
  constexpr float TH_ = -0.87758256189037276f;       // cos(pi - 0.5)
  constexpr float FALLB = 30.0f * 0.47942553860420301f * 0.5f;  // S*sin(m)*m

#pragma unroll
  for (int i = 0; i < 4; ++i) {
#pragma unroll
    for (int rg = 0; rg < 4; ++rg) {
      const int lrow = wm + 16 * i + 4 * kq + rg;
      const int row_lbl = label[m0 + lrow];   // L1-broadcast across the 16 ln lanes
      float* const orow = out + (size_t)(m0 + lrow) * NCLS;
#pragma unroll
      for (int j = 0; j < 4; ++j) {
        const int gcol = n0 + wn + 16 * j + ln;
        if (gcol < NCLS) {
          const float cosv = acc[i][j][rg];
          float o = S_ * cosv;
          if (gcol == row_lbl) {
            const float s2 = fmaxf(1.0f - cosv * cosv, 0.0f);
            const float sine = sqrtf(s2);
            float phi = cosv * COS_M - sine * SIN_M;
            phi = (cosv > TH_) ? phi : (cosv - FALLB);
            o = S_ * phi;
          }
          orow[gcol] = o;
        }
      }
    }
  }
}

// ---- Fallback kernel (ws too small for packed W): proven fused version, row-major A ----
__global__ __launch_bounds__(256) void arcface_gemm(const u16* __restrict__ Abf,
                                                    const float* __restrict__ W,
                                                    const int* __restrict__ label,
                                                    float* __restrict__ out) {
  __shared__ u16 lA[BM * LDST];
  __shared__ u16 lW[BN * LDST];
  __shared__ float rnw[BN];
  __shared__ int lbl[BM];

  const int tid = threadIdx.x;
  const int m0 = blockIdx.x * BM;
  const int n0 = blockIdx.y * BN;

  if (tid < BM) lbl[tid] = label[m0 + tid];

  const int r = tid >> 1;
  const int half = tid & 1;
  int c = n0 + r;
  if (c >= NCLS) c = NCLS - 1;

  const u16* aptr = Abf + (size_t)(m0 + r) * KDIM + half * 16;
  const float* wptr = W + (size_t)c * KDIM + half * 16;

  uint4 a0 = *(const uint4*)(aptr);
  uint4 a1 = *(const uint4*)(aptr + 8);
  float4 w0 = *(const float4*)(wptr);
  float4 w1 = *(const float4*)(wptr + 4);
  float4 w2 = *(const float4*)(wptr + 8);
  float4 w3 = *(const float4*)(wptr + 12);

  f32x4 acc[4][4] = {};
  float ss = 0.0f;

  const int lane = tid & 63;
  const int wv = tid >> 6;
  const int wm = (wv & 1) * 64;
  const int wn = (wv >> 1) * 64;
  const int ln = lane & 15;
  const int kq = lane >> 4;

  const int aw = r * LDST + half * 16;

  for (int kt = 0; kt < KDIM / BK; ++kt) {
    __syncthreads();
    *(uint4*)&lA[aw] = a0;
    *(uint4*)&lA[aw + 8] = a1;
    ss += w0.x * w0.x + w0.y * w0.y + w0.z * w0.z + w0.w * w0.w;
    ss += w1.x * w1.x + w1.y * w1.y + w1.z * w1.z + w1.w * w1.w;
    ss += w2.x * w2.x + w2.y * w2.y + w2.z * w2.z + w2.w * w2.w;
    ss += w3.x * w3.x + w3.y * w3.y + w3.z * w3.z + w3.w * w3.w;
    uint4 p0, p1;
    p0.x = pk2(w0.x, w0.y); p0.y = pk2(w0.z, w0.w);
    p0.z = pk2(w1.x, w1.y); p0.w = pk2(w1.z, w1.w);
    p1.x = pk2(w2.x, w2.y); p1.y = pk2(w2.z, w2.w);
    p1.z = pk2(w3.x, w3.y); p1.w = pk2(w3.z, w3.w);
    *(uint4*)&lW[aw] = p0;
    *(uint4*)&lW[aw + 8] = p1;
    __syncthreads();

    if (kt < KDIM / BK - 1) {
      const u16* ap = aptr + (kt + 1) * BK;
      a0 = *(const uint4*)(ap);
      a1 = *(const uint4*)(ap + 8);
      const float* wp = wptr + (kt + 1) * BK;
      w0 = *(const float4*)(wp);
      w1 = *(const float4*)(wp + 4);
      w2 = *(const float4*)(wp + 8);
      w3 = *(const float4*)(wp + 12);
    }

    s16x8 af[4], wf[4];
#pragma unroll
    for (int i = 0; i < 4; ++i)
      af[i] = *(const s16x8*)&lA[(wm + 16 * i + ln) * LDST + kq * 8];
#pragma unroll
    for (int j = 0; j < 4; ++j)
      wf[j] = *(const s16x8*)&lW[(wn + 16 * j + ln) * LDST + kq * 8];
#pragma unroll
    for (int i = 0; i < 4; ++i)
#pragma unroll
      for (int j = 0; j < 4; ++j)
        acc[i][j] = __builtin_amdgcn_mfma_f32_16x16x32_bf16(af[i], wf[j], acc[i][j], 0, 0, 0);
  }

  const float sst = ss + __shfl_xor(ss, 1);
  if (half == 0) rnw[r] = 1.0f / fmaxf(sqrtf(sst), 1e-12f);
  __syncthreads();

  constexpr float S_ = 30.0f;
  constexpr float COS_M = 0.87758256189037276f;
  constexpr float SIN_M = 0.47942553860420301f;
  constexpr float TH_ = -0.87758256189037276f;
  constexpr float FALLB = 30.0f * 0.47942553860420301f * 0.5f;

#pragma unroll
  for (int i = 0; i < 4; ++i) {
    const int lrow_b = wm + 16 * i + 4 * kq;
#pragma unroll
    for (int j = 0; j < 4; ++j) {
      const int col = wn + 16 * j + ln;
      const int gcol = n0 + col;
      const float rw = rnw[col];
      if (gcol < NCLS) {
#pragma unroll
        for (int rg = 0; rg < 4; ++rg) {
          const int lrow = lrow_b + rg;
          const float cosv = acc[i][j][rg] * rw;
          float o = S_ * cosv;
          if (gcol == lbl[lrow]) {
            const float s2 = fmaxf(1.0f - cosv * cosv, 0.0f);
            const float sine = sqrtf(s2);
            float phi = cosv * COS_M - sine * SIN_M;
            phi = (cosv > TH_) ? phi : (cosv - FALLB);
            o = S_ * phi;
          }
          out[(size_t)(m0 + lrow) * NCLS + gcol] = o;
        }
      }
    }
  }
}

extern "C" void kernel_launch(void* const* d_in, const int* in_sizes, int n_in,
                              void* d_out, int out_size, void* d_ws, size_t ws_size,
                              hipStream_t stream) {
  const float* input = (const float*)d_in[0];
  const int* label = (const int*)d_in[1];
  const float* weight = (const float*)d_in[2];
  float* out = (float*)d_out;

  // ws layout: [0,1MB) packed A | [1MB,2MB) row-major A (fallback) | [2MB,+102.4MB) packed W
  u32* apk = (u32*)d_ws;
  u32* arm = apk + (size_t)MDIM * KDIM / 2;
  u16* wpk = (u16*)(arm + (size_t)MDIM * KDIM / 2);

  hipLaunchKernelGGL(norm_input_kernel, dim3(MDIM), dim3(256), 0, stream, input, apk, arm);

  const size_t need = (size_t)2 * MDIM * KDIM * sizeof(u16) + (size_t)NCLS * KDIM * sizeof(u16);
  if (ws_size >= need) {
    hipLaunchKernelGGL(norm_weight_kernel, dim3((NGRPW + 3) / 4), dim3(256), 0, stream,
                       weight, wpk);
    hipLaunchKernelGGL(arcface_gemm_bf16, dim3(NWG), dim3(256), 0, stream,
                       (const u16*)apk, wpk, label, out);
  } else {
    dim3 grid(MDIM / BM, (NCLS + BN - 1) / BN);
    hipLaunchKernelGGL(arcface_gemm, grid, dim3(256), 0, stream, (const u16*)arm, weight, label, out);
  }
}

// Round 10
// 848.174 us; speedup vs baseline: 1.0997x; 1.0172x over previous
//
#include <hip/hip_runtime.h>

// ArcMarginProduct: out[b,c] = S * (c==label[b] ? phi : cos)
//   cos = <input_b/||input_b||, weight_c/||weight_c||>
//   phi = cos*cos(m) - sine*sin(m), fallback cos - S*sin(m)*m if cos <= cos(pi-m)
// B=1024, D=512, C=100000. fp32 in/out; bf16 MFMA inside.
//
// R1/R2: prenorm W to bf16 (FETCH 804->55 MB), XCD swizzle, 286 us gemm.
// R3/R5/R6: gl16 staging + counted-vmcnt pipelines: 257-315 us, pipes <20%.
// R7: zero-sync row-major gathers: 466 us (16-line divergent loads).
// R8: packed 1KB fragment tiles, zero-sync: 331 us. KEY DATUM: VGPR=80 —
//     compiler had 16 spare regs for 8 live fragments -> serial load-wait-use
//     chain, zero MLP. Block wall 34 us = 192 VMEM x ~400cyc: pure latency.
// R9: explicit software pipeline — named cur/next fragment sets, next K-step's
//     8 coalesced loads issued BEFORE current MFMA block, rotate at bottom.
//     launch_bounds(256,3): budget 64 acc + 32 cur + 32 next + addr ~= 145 reg.
//     Zero-sync retained (no LDS, no barriers).
// R10: resubmit of R9 — GPUAcquisitionTimeout (infra), kernel never ran.

#define MDIM 1024
#define KDIM 512
#define NCLS 100000
#define NGRPW (NCLS / 16)   // 6250 W row-groups (exact)

#define BM 128
#define BN 128
#define BK 32
#define LDST 40   // fallback kernel only: padded row stride

#define NTILES ((NCLS + BN - 1) / BN)   // 782
#define NWG (8 * NTILES)                // 6256, divisible by 8

typedef unsigned short u16;
typedef unsigned int u32;
typedef short s16x8 __attribute__((ext_vector_type(8)));
typedef float f32x4 __attribute__((ext_vector_type(4)));

// round-to-nearest-even fp32 -> bf16, two values packed into a u32
__device__ __forceinline__ u32 pk2(float a, float b) {
  u32 ua = __builtin_bit_cast(u32, a);
  u32 ub = __builtin_bit_cast(u32, b);
  ua += 0x7FFFu + ((ua >> 16) & 1u);
  ub += 0x7FFFu + ((ub >> 16) & 1u);
  return (ua >> 16) | (ub & 0xFFFF0000u);
}

// ---- Kernel 1: L2-normalize input rows; write PACKED tiles + row-major copy ----
// Packed layout: tile t = (rowgroup g)*16 + kt is 1KB = 256 u32:
//   u32 idx = t*256 + kq*64 + (row&15)*4 + sub   (elems kt*32+kq*8+2*sub..+1)
// Thread tid holds elems 2tid..2tid+1 of its row: kt=tid>>4, kq=(tid>>2)&3, sub=tid&3.
__global__ __launch_bounds__(256) void norm_input_kernel(const float* __restrict__ in,
                                                         u32* __restrict__ apk,
                                                         u32* __restrict__ arm) {
  const int row = blockIdx.x;
  const int tid = threadIdx.x;
  const float2 v = *reinterpret_cast<const float2*>(in + (size_t)row * KDIM + 2 * tid);
  float ss = v.x * v.x + v.y * v.y;
#pragma unroll
  for (int off = 32; off > 0; off >>= 1) ss += __shfl_down(ss, off);
  __shared__ float part[4];
  if ((tid & 63) == 0) part[tid >> 6] = ss;
  __syncthreads();
  const float tot = part[0] + part[1] + part[2] + part[3];
  const float rn = 1.0f / fmaxf(sqrtf(tot), 1e-12f);  // F.normalize: x / max(||x||, eps)
  const u32 val = pk2(v.x * rn, v.y * rn);
  const int g = row >> 4, lnr = row & 15;
  const int kt = tid >> 4, kq = (tid >> 2) & 3, sub = tid & 3;
  apk[((g * 16 + kt) << 8) + (kq << 6) + (lnr << 2) + sub] = val;
  arm[row * (KDIM / 2) + tid] = val;  // row-major copy for the fallback kernel
}

// ---- Kernel 1b: L2-normalize W rows; write PACKED fragment tiles ----
// One wave per 16-row group G. Lane l=(kq*16+ln) owns row 16G+ln, k-slice kq.
// Pass 1: accumulate sum-of-squares (lane covers 1/4 of its row), reduce over
// the 4 kq-lanes sharing ln via shfl_xor(16),(32). Pass 2: re-read (LLC-warm),
// scale, write tile (G,kt): 64 lanes x 16B = coalesced 1KB store.
__global__ __launch_bounds__(256) void norm_weight_kernel(const float* __restrict__ W,
                                                          u16* __restrict__ wpk) {
  const int G = blockIdx.x * 4 + (threadIdx.x >> 6);
  if (G >= NGRPW) return;   // no barriers below: divergent exit safe
  const int lane = threadIdx.x & 63;
  const int ln = lane & 15;
  const int kq = lane >> 4;
  const float* rp = W + (size_t)(16 * G + ln) * KDIM + kq * 8;
  float ss = 0.0f;
#pragma unroll
  for (int kt = 0; kt < 16; ++kt) {
    const float4 a = *reinterpret_cast<const float4*>(rp + kt * 32);
    const float4 b = *reinterpret_cast<const float4*>(rp + kt * 32 + 4);
    ss += a.x * a.x + a.y * a.y + a.z * a.z + a.w * a.w
        + b.x * b.x + b.y * b.y + b.z * b.z + b.w * b.w;
  }
  ss += __shfl_xor(ss, 16);
  ss += __shfl_xor(ss, 32);   // now = full-row sum for row 16G+ln
  const float rn = 1.0f / fmaxf(sqrtf(ss), 1e-12f);
#pragma unroll
  for (int kt = 0; kt < 16; ++kt) {
    const float4 a = *reinterpret_cast<const float4*>(rp + kt * 32);
    const float4 b = *reinterpret_cast<const float4*>(rp + kt * 32 + 4);
    uint4 o;
    o.x = pk2(a.x * rn, a.y * rn);
    o.y = pk2(a.z * rn, a.w * rn);
    o.z = pk2(b.x * rn, b.y * rn);
    o.w = pk2(b.z * rn, b.w * rn);
    *reinterpret_cast<uint4*>(wpk + (((size_t)G * 16 + kt) << 9) + lane * 8) = o;
  }
}

// ---- Kernel 2 (main): C = Apk * Wpk^T, both packed bf16, fused ArcFace epilogue ----
// 128x128 per block, 4 waves 2x2, each wave an independent 64x64 via 4x4 of
// 16x16x32 MFMA. No LDS, no barriers. Every fragment load is base + lane*16B
// over a 1KB packed tile (8 contiguous lines). Software pipeline: next K-step's
// 8 loads issued before current MFMA block (cur/next named sets, full unroll).
// Grid: 1D, bijective XCD swizzle, M fastest within an XCD (W L2-resident).
__global__ __launch_bounds__(256, 3) void arcface_gemm_bf16(const u16* __restrict__ Apk,
                                                            const u16* __restrict__ Wpk,
                                                            const int* __restrict__ label,
                                                            float* __restrict__ out) {
  const int tid = threadIdx.x;
  const int orig = blockIdx.x;
  const int wg = (orig & 7) * NTILES + (orig >> 3);
  const int m0 = (wg & 7) * BM;
  const int n0 = (wg >> 3) * BN;

  const int lane = tid & 63;
  const int wv = tid >> 6;
  const int wm = (wv & 1) * 64;
  const int wn = (wv >> 1) * 64;
  const int ln = lane & 15;   // C/D col
  const int kq = lane >> 4;   // C/D row-group

  // fragment tile bases: tile index = group*16 + kt, tile = 512 u16 elems
  const u16* aT = Apk + ((size_t)((m0 + wm) >> 4) << 13) + lane * 8;
  const u16* wT0;
  const u16* wT1;
  const u16* wT2;
  const u16* wT3;
  {
    const int gbase = (n0 + wn) >> 4;
    int g0 = gbase, g1 = gbase + 1, g2 = gbase + 2, g3 = gbase + 3;
    if (g1 > NGRPW - 1) g1 = NGRPW - 1;   // clamp loads on last N-tile; stores guarded
    if (g2 > NGRPW - 1) g2 = NGRPW - 1;
    if (g3 > NGRPW - 1) g3 = NGRPW - 1;
    wT0 = Wpk + ((size_t)g0 << 13) + lane * 8;
    wT1 = Wpk + ((size_t)g1 << 13) + lane * 8;
    wT2 = Wpk + ((size_t)g2 << 13) + lane * 8;
    wT3 = Wpk + ((size_t)g3 << 13) + lane * 8;
  }

  f32x4 acc[4][4] = {};

  // prologue: load K-step 0 into cur
  s16x8 ca[4], cw[4], na[4], nw[4];
#pragma unroll
  for (int i = 0; i < 4; ++i) ca[i] = *(const s16x8*)(aT + ((i * 16 + 0) << 9));
  cw[0] = *(const s16x8*)(wT0);
  cw[1] = *(const s16x8*)(wT1);
  cw[2] = *(const s16x8*)(wT2);
  cw[3] = *(const s16x8*)(wT3);

#pragma unroll
  for (int kt = 0; kt < KDIM / BK; ++kt) {
    if (kt < KDIM / BK - 1) {   // issue next K-step's loads BEFORE the MFMA block
      const int nk = kt + 1;
#pragma unroll
      for (int i = 0; i < 4; ++i) na[i] = *(const s16x8*)(aT + ((i * 16 + nk) << 9));
      nw[0] = *(const s16x8*)(wT0 + (nk << 9));
      nw[1] = *(const s16x8*)(wT1 + (nk << 9));
      nw[2] = *(const s16x8*)(wT2 + (nk << 9));
      nw[3] = *(const s16x8*)(wT3 + (nk << 9));
    }
#pragma unroll
    for (int i = 0; i < 4; ++i)
#pragma unroll
      for (int j = 0; j < 4; ++j)
        acc[i][j] = __builtin_amdgcn_mfma_f32_16x16x32_bf16(ca[i], cw[j], acc[i][j], 0, 0, 0);
#pragma unroll
    for (int i = 0; i < 4; ++i) ca[i] = na[i];
#pragma unroll
    for (int j = 0; j < 4; ++j) cw[j] = nw[j];
  }

  // epilogue: C/D layout col = lane&15, row = (lane>>4)*4 + reg  [verified m89/m91]
  constexpr float S_ = 30.0f;
  constexpr float COS_M = 0.87758256189037276f;
  constexpr float SIN_M = 0.47942553860420301f;
  constexpr float TH_ = -0.87758256189037276f;       // cos(pi - 0.5)
  constexpr float FALLB = 30.0f * 0.47942553860420301f * 0.5f;  // S*sin(m)*m

#pragma unroll
  for (int i = 0; i < 4; ++i) {
#pragma unroll
    for (int rg = 0; rg < 4; ++rg) {
      const int lrow = wm + 16 * i + 4 * kq + rg;
      const int row_lbl = label[m0 + lrow];   // L1-broadcast across the 16 ln lanes
      float* const orow = out + (size_t)(m0 + lrow) * NCLS;
#pragma unroll
      for (int j = 0; j < 4; ++j) {
        const int gcol = n0 + wn + 16 * j + ln;
        if (gcol < NCLS) {
          const float cosv = acc[i][j][rg];
          float o = S_ * cosv;
          if (gcol == row_lbl) {
            const float s2 = fmaxf(1.0f - cosv * cosv, 0.0f);
            const float sine = sqrtf(s2);
            float phi = cosv * COS_M - sine * SIN_M;
            phi = (cosv > TH_) ? phi : (cosv - FALLB);
            o = S_ * phi;
          }
          orow[gcol] = o;
        }
      }
    }
  }
}

// ---- Fallback kernel (ws too small for packed W): proven fused version, row-major A ----
__global__ __launch_bounds__(256) void arcface_gemm(const u16* __restrict__ Abf,
                                                    const float* __restrict__ W,
                                                    const int* __restrict__ label,
                                                    float* __restrict__ out) {
  __shared__ u16 lA[BM * LDST];
  __shared__ u16 lW[BN * LDST];
  __shared__ float rnw[BN];
  __shared__ int lbl[BM];

  const int tid = threadIdx.x;
  const int m0 = blockIdx.x * BM;
  const int n0 = blockIdx.y * BN;

  if (tid < BM) lbl[tid] = label[m0 + tid];

  const int r = tid >> 1;
  const int half = tid & 1;
  int c = n0 + r;
  if (c >= NCLS) c = NCLS - 1;

  const u16* aptr = Abf + (size_t)(m0 + r) * KDIM + half * 16;
  const float* wptr = W + (size_t)c * KDIM + half * 16;

  uint4 a0 = *(const uint4*)(aptr);
  uint4 a1 = *(const uint4*)(aptr + 8);
  float4 w0 = *(const float4*)(wptr);
  float4 w1 = *(const float4*)(wptr + 4);
  float4 w2 = *(const float4*)(wptr + 8);
  float4 w3 = *(const float4*)(wptr + 12);

  f32x4 acc[4][4] = {};
  float ss = 0.0f;

  const int lane = tid & 63;
  const int wv = tid >> 6;
  const int wm = (wv & 1) * 64;
  const int wn = (wv >> 1) * 64;
  const int ln = lane & 15;
  const int kq = lane >> 4;

  const int aw = r * LDST + half * 16;

  for (int kt = 0; kt < KDIM / BK; ++kt) {
    __syncthreads();
    *(uint4*)&lA[aw] = a0;
    *(uint4*)&lA[aw + 8] = a1;
    ss += w0.x * w0.x + w0.y * w0.y + w0.z * w0.z + w0.w * w0.w;
    ss += w1.x * w1.x + w1.y * w1.y + w1.z * w1.z + w1.w * w1.w;
    ss += w2.x * w2.x + w2.y * w2.y + w2.z * w2.z + w2.w * w2.w;
    ss += w3.x * w3.x + w3.y * w3.y + w3.z * w3.z + w3.w * w3.w;
    uint4 p0, p1;
    p0.x = pk2(w0.x, w0.y); p0.y = pk2(w0.z, w0.w);
    p0.z = pk2(w1.x, w1.y); p0.w = pk2(w1.z, w1.w);
    p1.x = pk2(w2.x, w2.y); p1.y = pk2(w2.z, w2.w);
    p1.z = pk2(w3.x, w3.y); p1.w = pk2(w3.z, w3.w);
    *(uint4*)&lW[aw] = p0;
    *(uint4*)&lW[aw + 8] = p1;
    __syncthreads();

    if (kt < KDIM / BK - 1) {
      const u16* ap = aptr + (kt + 1) * BK;
      a0 = *(const uint4*)(ap);
      a1 = *(const uint4*)(ap + 8);
      const float* wp = wptr + (kt + 1) * BK;
      w0 = *(const float4*)(wp);
      w1 = *(const float4*)(wp + 4);
      w2 = *(const float4*)(wp + 8);
      w3 = *(const float4*)(wp + 12);
    }

    s16x8 af[4], wf[4];
#pragma unroll
    for (int i = 0; i < 4; ++i)
      af[i] = *(const s16x8*)&lA[(wm + 16 * i + ln) * LDST + kq * 8];
#pragma unroll
    for (int j = 0; j < 4; ++j)
      wf[j] = *(const s16x8*)&lW[(wn + 16 * j + ln) * LDST + kq * 8];
#pragma unroll
    for (int i = 0; i < 4; ++i)
#pragma unroll
      for (int j = 0; j < 4; ++j)
        acc[i][j] = __builtin_amdgcn_mfma_f32_16x16x32_bf16(af[i], wf[j], acc[i][j], 0, 0, 0);
  }

  const float sst = ss + __shfl_xor(ss, 1);
  if (half == 0) rnw[r] = 1.0f / fmaxf(sqrtf(sst), 1e-12f);
  __syncthreads();

  constexpr float S_ = 30.0f;
  constexpr float COS_M = 0.87758256189037276f;
  constexpr float SIN_M = 0.47942553860420301f;
  constexpr float TH_ = -0.87758256189037276f;
  constexpr float FALLB = 30.0f * 0.47942553860420301f * 0.5f;

#pragma unroll
  for (int i = 0; i < 4; ++i) {
    const int lrow_b = wm + 16 * i + 4 * kq;
#pragma unroll
    for (int j = 0; j < 4; ++j) {
      const int col = wn + 16 * j + ln;
      const int gcol = n0 + col;
      const float rw = rnw[col];
      if (gcol < NCLS) {
#pragma unroll
        for (int rg = 0; rg < 4; ++rg) {
          const int lrow = lrow_b + rg;
          const float cosv = acc[i][j][rg] * rw;
          float o = S_ * cosv;
          if (gcol == lbl[lrow]) {
            const float s2 = fmaxf(1.0f - cosv * cosv, 0.0f);
            const float sine = sqrtf(s2);
            float phi = cosv * COS_M - sine * SIN_M;
            phi = (cosv > TH_) ? phi : (cosv - FALLB);
            o = S_ * phi;
          }
          out[(size_t)(m0 + lrow) * NCLS + gcol] = o;
        }
      }
    }
  }
}

extern "C" void kernel_launch(void* const* d_in, const int* in_sizes, int n_in,
                              void* d_out, int out_size, void* d_ws, size_t ws_size,
                              hipStream_t stream) {
  const float* input = (const float*)d_in[0];
  const int* label = (const int*)d_in[1];
  const float* weight = (const float*)d_in[2];
  float* out = (float*)d_out;

  // ws layout: [0,1MB) packed A | [1MB,2MB) row-major A (fallback) | [2MB,+102.4MB) packed W
  u32* apk = (u32*)d_ws;
  u32* arm = apk + (size_t)MDIM * KDIM / 2;
  u16* wpk = (u16*)(arm + (size_t)MDIM * KDIM / 2);

  hipLaunchKernelGGL(norm_input_kernel, dim3(MDIM), dim3(256), 0, stream, input, apk, arm);

  const size_t need = (size_t)2 * MDIM * KDIM * sizeof(u16) + (size_t)NCLS * KDIM * sizeof(u16);
  if (ws_size >= need) {
    hipLaunchKernelGGL(norm_weight_kernel, dim3((NGRPW + 3) / 4), dim3(256), 0, stream,
                       weight, wpk);
    hipLaunchKernelGGL(arcface_gemm_bf16, dim3(NWG), dim3(256), 0, stream,
                       (const u16*)apk, wpk, label, out);
  } else {
    dim3 grid(MDIM / BM, (NCLS + BN - 1) / BN);
    hipLaunchKernelGGL(arcface_gemm, grid, dim3(256), 0, stream, (const u16*)arm, weight, label, out);
  }
}